// Round 6
// baseline (343.149 us; speedup 1.0000x reference)
//
#include <hip/hip_runtime.h>

typedef unsigned short u16;
typedef __attribute__((ext_vector_type(8))) short bf16x8;
typedef __attribute__((ext_vector_type(4))) float f32x4;
typedef __attribute__((ext_vector_type(8))) unsigned short u16x8;

#define MFMA16(a, b, c) __builtin_amdgcn_mfma_f32_16x16x32_bf16((a), (b), (c), 0, 0, 0)

// d_ws layout (u16 element offsets). All operands PRE-PACKED in per-fragment
// order so every B-load in k_fused is a wave-contiguous 1KB burst.
//   dense W, col-pair w (32 cols), k-step kk, nt: elem (((w*8+kk)*2+nt)*64+lane)*8+j
//            <- W[w*32+nt*16+(lane&15)][kk*32+((lane>>4)&3)*8+j]
//   Wc1, col-group cw (0..7): elem ((cw*8+kk)*64+lane)*8+j
//   KN/VT (per head h): elem (((h*2+kk)*4+nt)*64+lane)*8+j
#define OFF_WQ   0
#define OFF_WG   65536
#define OFF_WC1  131072
#define OFF_WO   163840
#define OFF_KNF  229376
#define OFF_VTF  245760
#define OFF_KND  262144
#define OFF_VTD  278528

__device__ __forceinline__ u16 f2b(float f) {
  union { float f; unsigned u; } v; v.f = f;
  unsigned r = v.u + 0x7fffu + ((v.u >> 16) & 1u);  // RNE fp32->bf16
  return (u16)(r >> 16);
}
__device__ __forceinline__ unsigned pk2(float lo, float hi) {  // 2x f32 -> packed bf16 (RNE)
  unsigned r;
  asm("v_cvt_pk_bf16_f32 %0, %1, %2" : "=v"(r) : "v"(lo), "v"(hi));
  return r;
}
__device__ __forceinline__ float fsig(float x) {
  return __builtin_amdgcn_rcpf(1.f + __expf(-x));
}
__device__ __forceinline__ float ftanh(float x) {
  float e = __expf(2.f * x);
  return (e - 1.f) * __builtin_amdgcn_rcpf(e + 1.f);
}
__device__ __forceinline__ float sum16(float v) {
  v += __shfl_xor(v, 1);
  v += __shfl_xor(v, 2);
  v += __shfl_xor(v, 4);
  v += __shfl_xor(v, 8);
  return v;
}

// ---------- pre-kernel: convert+pack weights; norm/pack keys; transpose/pack vals ----------
__global__ void k_prep(const float* __restrict__ Wq, const float* __restrict__ Wg,
                       const float* __restrict__ Wc1, const float* __restrict__ Wo,
                       const float* __restrict__ fk, const float* __restrict__ fv,
                       const float* __restrict__ dk, const float* __restrict__ dv,
                       u16* __restrict__ ws) {
  const int bid = blockIdx.x, t = threadIdx.x;
  if (bid < 96) {  // Wq/Wg/Wo: 8192 16B-chunks each, 32 blocks each
    const float* W = bid < 32 ? Wq : (bid < 64 ? Wg : Wo);
    const int OFF = bid < 32 ? OFF_WQ : (bid < 64 ? OFF_WG : OFF_WO);
    int c = (bid & 31) * 256 + t;
    int lane = c & 63, nt = (c >> 6) & 1, kk = (c >> 7) & 7, w = c >> 10;
    const float* s = W + (w * 32 + nt * 16 + (lane & 15)) * 256 + kk * 32 + ((lane >> 4) & 3) * 8;
    u16x8 o;
    #pragma unroll
    for (int j = 0; j < 8; ++j) o[j] = f2b(s[j]);
    *(u16x8*)(ws + OFF + c * 8) = o;
  } else if (bid < 112) {  // Wc1: 4096 chunks, 16 blocks
    int c = (bid - 96) * 256 + t;
    int lane = c & 63, kk = (c >> 6) & 7, w = c >> 9;
    const float* s = Wc1 + (w * 16 + (lane & 15)) * 256 + kk * 32 + ((lane >> 4) & 3) * 8;
    u16x8 o;
    #pragma unroll
    for (int j = 0; j < 8; ++j) o[j] = f2b(s[j]);
    *(u16x8*)(ws + OFF_WC1 + c * 8) = o;
  } else {  // keys/vals: 1024 (structure,row) units, one wave each
    int unit = (bid - 112) * 4 + (t >> 6);
    int lane = t & 63;
    int st = unit >> 8, rowid = unit & 255;
    int hh = rowid >> 6, s = rowid & 63;
    if (st < 2) {  // keys: coalesced load, wave-reduce norm, 1 scattered store/lane
      const float* p = (st == 0 ? fk : dk) + rowid * 64;
      float x = p[lane];
      float v = x * x;
      v += __shfl_xor(v, 1);  v += __shfl_xor(v, 2);  v += __shfl_xor(v, 4);
      v += __shfl_xor(v, 8);  v += __shfl_xor(v, 16); v += __shfl_xor(v, 32);
      float sc = __builtin_amdgcn_rcpf(__builtin_amdgcn_sqrtf(v) + 1e-8f);
      int nt = s >> 4, kk = lane >> 5, lo = ((lane >> 3) & 3) * 16 + (s & 15), j = lane & 7;
      ws[(st == 0 ? OFF_KNF : OFF_KND) + (((hh * 2 + kk) * 4 + nt) * 64 + lo) * 8 + j] =
          f2b(x * sc);
    } else {  // vals: transpose scatter, 1 store/lane
      const float* p = (st == 2 ? fv : dv) + rowid * 64;
      int kk = s >> 5, qd = (s >> 3) & 3, j = s & 7;
      int lo = qd * 16 + (lane & 15), nt = lane >> 4;
      ws[(st == 2 ? OFF_VTF : OFF_VTD) + (((hh * 2 + kk) * 4 + nt) * 64 + lo) * 8 + j] =
          f2b(p[lane]);
    }
  }
}

// ---------- fused main kernel ----------
// 1024 blocks x 512 threads (8 waves); 64 rows/block.
// 3-blocks/CU design: LDS 52.5KB (single M buffer ctx->query->out_pre + 16KB
// 2KB/wave chunks) and __launch_bounds__(512,6) (<=85 unified regs, every
// phase's structural live-set <=~80 -> no spill).
// gate/conf + Wo: wave w owns output cols [w*32, w*32+32).
// Wq + attention: wave w owns head hd=w&3, rows rb=(w>>2)*32..+31, processed
// as two 16-row halves; half-1's normalized q is held in regs during half-0
// (chunk holds only 16 rows).
__global__ __launch_bounds__(512, 6)
void k_fused(const float* __restrict__ query, const float* __restrict__ context,
             const float* __restrict__ bq, const float* __restrict__ bg,
             const float* __restrict__ bc1, const float* __restrict__ Wc2,
             const float* __restrict__ bc2v, const float* __restrict__ bo,
             const float* __restrict__ mixl, const u16* __restrict__ ws,
             float* __restrict__ outp) {
  extern __shared__ char smem[];
  char* Mb = smem;                                   // 32 KB: ctx -> query -> out_pre
  char* Cb = smem + 32768;                           // 16 KB: 8 x 2KB wave chunks (q,P; 16 rows)
  float (*red_a)[64] = (float(*)[64])(smem + 49152); // [8][64] gate partials
  float (*red_c)[64] = (float(*)[64])(smem + 51200); // [8][64] conf partials
  float* sA = (float*)(smem + 53248);                // [64] conf*mix
  float* sB = (float*)(smem + 53504);                // [64] conf*(1-mix)  (total 53760 B)

  const int t = threadIdx.x;
  const int w = t >> 6;
  const int lane = t & 63;
  const int quad = lane >> 4;
  const int l16 = lane & 15;
  const int row4 = quad * 4;
  const int l16e = l16 & ~1;
  const int oddl = lane & 1;
  const int hd = w & 3;             // attention head
  const int rb = (w >> 2) * 32;     // attention row base
  const int blk = blockIdx.x;
  char* Ch = Cb + w * 2048;         // wave-private 16x64 bf16 chunk, swizzled

  auto ldA = [&](int row, int kb) {  // A-frag from M: m=row, k=kb..kb+7
    return *(const bf16x8*)(Mb + row * 512 + ((((kb >> 3) ^ (row & 7)) << 4)));
  };
  auto ldCh = [&](int row, int kb) {  // A-frag from own chunk (16 rows)
    return *(const bf16x8*)(Ch + row * 128 + ((((kb >> 3) ^ (row & 7)) << 4)));
  };
  // packed pair-lane b32 write of 4 values at cols {nt*16+l16} into own chunk
  auto st4c = [&](int row, float v0, float v1, float v2, float v3) {
    float o0 = __shfl_xor(v0, 1), o1 = __shfl_xor(v1, 1);
    float o2 = __shfl_xor(v2, 1), o3 = __shfl_xor(v3, 1);
    float lo0 = oddl ? o1 : v0, hi0 = oddl ? v1 : o0;
    float lo1 = oddl ? o3 : v2, hi1 = oddl ? v3 : o2;
    int c0 = (oddl ? 16 : 0) + l16e, c1 = (oddl ? 48 : 32) + l16e;
    *(unsigned*)(Ch + row * 128 + ((((c0 >> 3) ^ (row & 7)) << 4) | ((c0 & 7) << 1))) = pk2(lo0, hi0);
    *(unsigned*)(Ch + row * 128 + ((((c1 >> 3) ^ (row & 7)) << 4) | ((c1 & 7) << 1))) = pk2(lo1, hi1);
  };
  auto st4m = [&](int row, int cb, float v0, float v1, float v2, float v3) {
    float o0 = __shfl_xor(v0, 1), o1 = __shfl_xor(v1, 1);
    float o2 = __shfl_xor(v2, 1), o3 = __shfl_xor(v3, 1);
    float lo0 = oddl ? o1 : v0, hi0 = oddl ? v1 : o0;
    float lo1 = oddl ? o3 : v2, hi1 = oddl ? v3 : o2;
    int c0 = cb + (oddl ? 16 : 0) + l16e, c1 = cb + (oddl ? 48 : 32) + l16e;
    *(unsigned*)(Mb + row * 512 + ((((c0 >> 3) ^ (row & 7)) << 4) | ((c0 & 7) << 1))) = pk2(lo0, hi0);
    *(unsigned*)(Mb + row * 512 + ((((c1 >> 3) ^ (row & 7)) << 4) | ((c1 & 7) << 1))) = pk2(lo1, hi1);
  };

  const f32x4 vzero = {0.f, 0.f, 0.f, 0.f};

  // ===== entry: prefetch gate kk=0 B-frags; stage context into M =====
  bf16x8 pg0 = *(const bf16x8*)(ws + OFF_WG + ((w * 16 + 0) * 64 + lane) * 8);
  bf16x8 pg1 = *(const bf16x8*)(ws + OFF_WG + ((w * 16 + 1) * 64 + lane) * 8);
  bf16x8 pc0 = *(const bf16x8*)(ws + OFF_WC1 + ((w * 8) * 64 + lane) * 8);
  {
    const float* src = context + (size_t)blk * 16384;
    #pragma unroll
    for (int i = 0; i < 8; ++i) {
      int e = i * 2048 + t * 4;
      float4 v = *(const float4*)(src + e);
      int row = e >> 8, col = e & 255;
      uint2 pk;
      pk.x = pk2(v.x, v.y);
      pk.y = pk2(v.z, v.w);
      *(uint2*)(Mb + row * 512 + ((((col >> 3) ^ (row & 7)) << 4) | ((col & 7) << 1))) = pk;
    }
  }
  float bgv[2], bov[2], bq4[4];
  #pragma unroll
  for (int nt = 0; nt < 2; ++nt) {
    int n = w * 32 + nt * 16 + l16;
    bgv[nt] = bg[n]; bov[nt] = bo[n];
  }
  #pragma unroll
  for (int nt = 0; nt < 4; ++nt) bq4[nt] = bq[hd * 64 + nt * 16 + l16];
  float bc1v = bc1[w * 16 + l16];
  float wc2v = Wc2[w * 16 + l16];
  __syncthreads();  // bar1: ctx staged

  // ===== gate + conf GEMMs on M (shared A-frags); T14 query load in epilogue =====
  float4 qv[8];
  {
    f32x4 ag[4][2], ac[4];
    #pragma unroll
    for (int mt = 0; mt < 4; ++mt) { ag[mt][0] = vzero; ag[mt][1] = vzero; ac[mt] = vzero; }
    #pragma unroll
    for (int kk = 0; kk < 8; ++kk) {
      int kb = kk * 32 + quad * 8;
      bf16x8 a0 = ldA(l16, kb), a1 = ldA(16 + l16, kb),
             a2 = ldA(32 + l16, kb), a3 = ldA(48 + l16, kb);
      bf16x8 b0 = kk ? *(const bf16x8*)(ws + OFF_WG + (((w * 8 + kk) * 2 + 0) * 64 + lane) * 8) : pg0;
      bf16x8 b1 = kk ? *(const bf16x8*)(ws + OFF_WG + (((w * 8 + kk) * 2 + 1) * 64 + lane) * 8) : pg1;
      bf16x8 bc = kk ? *(const bf16x8*)(ws + OFF_WC1 + ((w * 8 + kk) * 64 + lane) * 8) : pc0;
      ag[0][0] = MFMA16(a0, b0, ag[0][0]); ag[0][1] = MFMA16(a0, b1, ag[0][1]);
      ag[1][0] = MFMA16(a1, b0, ag[1][0]); ag[1][1] = MFMA16(a1, b1, ag[1][1]);
      ag[2][0] = MFMA16(a2, b0, ag[2][0]); ag[2][1] = MFMA16(a2, b1, ag[2][1]);
      ag[3][0] = MFMA16(a3, b0, ag[3][0]); ag[3][1] = MFMA16(a3, b1, ag[3][1]);
      ac[0] = MFMA16(a0, bc, ac[0]);
      ac[1] = MFMA16(a1, bc, ac[1]);
      ac[2] = MFMA16(a2, bc, ac[2]);
      ac[3] = MFMA16(a3, bc, ac[3]);
    }
    // gate reduce (consumes ag)
    #pragma unroll
    for (int mt = 0; mt < 4; ++mt)
      #pragma unroll
      for (int r = 0; r < 4; ++r) {
        float sg = ftanh(ag[mt][0][r] + bgv[0]) + ftanh(ag[mt][1][r] + bgv[1]);
        sg = sum16(sg);
        if (l16 == 0) red_a[w][mt * 16 + row4 + r] = sg;
      }
    // T14: issue query loads now (ag freed); latency hides under conf reduce + bar2
    {
      const float* qsrc = query + (size_t)blk * 16384;
      #pragma unroll
      for (int i = 0; i < 8; ++i) qv[i] = *(const float4*)(qsrc + i * 2048 + t * 4);
    }
    // conf reduce
    #pragma unroll
    for (int mt = 0; mt < 4; ++mt)
      #pragma unroll
      for (int r = 0; r < 4; ++r) {
        float sc = ftanh(ac[mt][r] + bc1v) * wc2v;
        sc = sum16(sc);
        if (l16 == 0) red_c[w][mt * 16 + row4 + r] = sc;
      }
  }
  __syncthreads();  // bar2: partials published; all M(ctx) reads done

  // ===== write query into M; wave0 combines mix/conf; prefetch Wq kk=0 =====
  #pragma unroll
  for (int i = 0; i < 8; ++i) {
    int e = i * 2048 + t * 4;
    int row = e >> 8, col = e & 255;
    uint2 pk;
    pk.x = pk2(qv[i].x, qv[i].y);
    pk.y = pk2(qv[i].z, qv[i].w);
    *(uint2*)(Mb + row * 512 + ((((col >> 3) ^ (row & 7)) << 4) | ((col & 7) << 1))) = pk;
  }
  if (t < 64) {
    float g = 0.f, cc = 0.f;
    #pragma unroll
    for (int i = 0; i < 8; ++i) { g += red_a[i][t]; cc += red_c[i][t]; }
    float mix = fsig(mixl[0] + g * (1.f / 256.f));
    float conf = fsig(cc + bc2v[0]);
    sA[t] = conf * mix;
    sB[t] = conf - conf * mix;
  }
  bf16x8 pq[4];
  #pragma unroll
  for (int nt = 0; nt < 4; ++nt) {
    int g = hd * 4 + nt;
    pq[nt] = *(const bf16x8*)(ws + OFF_WQ + ((((g >> 1) * 8) * 2 + (g & 1)) * 64 + lane) * 8);
  }
  __syncthreads();  // bar3: query staged; sA/sB ready

  // ===== Wq GEMM (rows rb..rb+31, head hd) + in-wave q-norm =====
  f32x4 qa[2][4];
  {
    #pragma unroll
    for (int mt = 0; mt < 2; ++mt)
      #pragma unroll
      for (int nt = 0; nt < 4; ++nt) qa[mt][nt] = vzero;
    #pragma unroll
    for (int kk = 0; kk < 8; ++kk) {
      int kb = kk * 32 + quad * 8;
      bf16x8 a0 = ldA(rb + l16, kb), a1 = ldA(rb + 16 + l16, kb);
      #pragma unroll
      for (int nt = 0; nt < 4; ++nt) {
        int g = hd * 4 + nt;
        bf16x8 b = kk ? *(const bf16x8*)(ws + OFF_WQ + ((((g >> 1) * 8 + kk) * 2 + (g & 1)) * 64 + lane) * 8)
                      : pq[nt];
        qa[0][nt] = MFMA16(a0, b, qa[0][nt]);
        qa[1][nt] = MFMA16(a1, b, qa[1][nt]);
      }
    }
    // q-norm: scale in place; write half-0 q to chunk; half-1 stays in regs
    #pragma unroll
    for (int mt = 0; mt < 2; ++mt)
      #pragma unroll
      for (int r = 0; r < 4; ++r) {
        float ss = 0.f;
        #pragma unroll
        for (int nt = 0; nt < 4; ++nt) {
          float q_ = qa[mt][nt][r] + bq4[nt];
          qa[mt][nt][r] = q_;
          ss += q_ * q_;
        }
        ss = sum16(ss);
        float scl = __builtin_amdgcn_rcpf(__builtin_amdgcn_sqrtf(ss) + 1e-8f);
        #pragma unroll
        for (int nt = 0; nt < 4; ++nt) qa[mt][nt][r] *= scl;
      }
    #pragma unroll
    for (int r = 0; r < 4; ++r)
      st4c(row4 + r, qa[0][0][r], qa[0][1][r], qa[0][2][r], qa[0][3][r]);
  }
  __syncthreads();  // bar4: all M(query) reads done -> M free for out_pre

  // ===== attention: wave-local; two 16-row halves sequential; tiers sequential =====
  #pragma unroll
  for (int half = 0; half < 2; ++half) {
    bf16x8 q0 = ldCh(l16, quad * 8);
    bf16x8 q1 = ldCh(l16, 32 + quad * 8);
    f32x4 oa[4];

    #pragma unroll
    for (int tier = 0; tier < 2; ++tier) {
      const u16* KN = ws + (tier == 0 ? OFF_KNF : OFF_KND);
      const u16* VT = ws + (tier == 0 ? OFF_VTF : OFF_VTD);

      // QK^T (cos sims bounded by 1 -> no max subtraction)
      f32x4 s4[4];
      #pragma unroll
      for (int nt = 0; nt < 4; ++nt) s4[nt] = vzero;
      #pragma unroll
      for (int kk = 0; kk < 2; ++kk)
        #pragma unroll
        for (int nt = 0; nt < 4; ++nt) {
          bf16x8 b = *(const bf16x8*)(KN + (((hd * 2 + kk) * 4 + nt) * 64 + lane) * 8);
          s4[nt] = MFMA16(kk ? q1 : q0, b, s4[nt]);
        }

      // softmax -> packed P into chunk (q rows overwritten; q lives in q0/q1)
      #pragma unroll
      for (int r = 0; r < 4; ++r) {
        float rs = 0.f;
        #pragma unroll
        for (int nt = 0; nt < 4; ++nt) { float e = __expf(s4[nt][r]); s4[nt][r] = e; rs += e; }
        rs = sum16(rs);
        float inv = __builtin_amdgcn_rcpf(rs);
        st4c(row4 + r, s4[0][r] * inv, s4[1][r] * inv, s4[2][r] * inv, s4[3][r] * inv);
      }

      // PV
      bf16x8 p0 = ldCh(l16, quad * 8);
      bf16x8 p1 = ldCh(l16, 32 + quad * 8);
      f32x4 pv4[4];
      #pragma unroll
      for (int nt = 0; nt < 4; ++nt) pv4[nt] = vzero;
      #pragma unroll
      for (int kk = 0; kk < 2; ++kk)
        #pragma unroll
        for (int nt = 0; nt < 4; ++nt) {
          bf16x8 b = *(const bf16x8*)(VT + (((hd * 2 + kk) * 4 + nt) * 64 + lane) * 8);
          pv4[nt] = MFMA16(kk ? p1 : p0, b, pv4[nt]);
        }

      // mix/conf scale; fast tier initializes oa, deep tier accumulates
      #pragma unroll
      for (int r = 0; r < 4; ++r) {
        int Rg = rb + half * 16 + row4 + r;
        float m_ = (tier == 0) ? sA[Rg] : sB[Rg];
        #pragma unroll
        for (int nt = 0; nt < 4; ++nt) {
          if (tier == 0) oa[nt][r] = m_ * pv4[nt][r];
          else           oa[nt][r] += m_ * pv4[nt][r];
        }
      }
    }

    if (half == 0) {  // chunk now dead -> stage half-1's q (wave-private, no barrier)
      #pragma unroll
      for (int r = 0; r < 4; ++r)
        st4c(row4 + r, qa[1][0][r], qa[1][1][r], qa[1][2][r], qa[1][3][r]);
    }
    // retire this half's out_pre into M (M free since bar4)
    #pragma unroll
    for (int r = 0; r < 4; ++r)
      st4m(rb + half * 16 + row4 + r, hd * 64, oa[0][r], oa[1][r], oa[2][r], oa[3][r]);
  }

  // prefetch Wo kk=0 B-frags across the barrier
  bf16x8 po0 = *(const bf16x8*)(ws + OFF_WO + (((w * 8) * 2 + 0) * 64 + lane) * 8);
  bf16x8 po1 = *(const bf16x8*)(ws + OFF_WO + (((w * 8) * 2 + 1) * 64 + lane) * 8);
  __syncthreads();  // bar5: out_pre complete

  // ===== final GEMM (Wo) on M =====
  {
    f32x4 o[4][2];
    #pragma unroll
    for (int mt = 0; mt < 4; ++mt) { o[mt][0] = vzero; o[mt][1] = vzero; }
    #pragma unroll
    for (int kk = 0; kk < 8; ++kk) {
      int kb = kk * 32 + quad * 8;
      bf16x8 a0 = ldA(l16, kb), a1 = ldA(16 + l16, kb),
             a2 = ldA(32 + l16, kb), a3 = ldA(48 + l16, kb);
      #pragma unroll
      for (int nt = 0; nt < 2; ++nt) {
        bf16x8 b = (kk == 0 && nt == 0) ? po0
                 : (kk == 0 && nt == 1) ? po1
                 : *(const bf16x8*)(ws + OFF_WO + (((w * 8 + kk) * 2 + nt) * 64 + lane) * 8);
        o[0][nt] = MFMA16(a0, b, o[0][nt]);
        o[1][nt] = MFMA16(a1, b, o[1][nt]);
        o[2][nt] = MFMA16(a2, b, o[2][nt]);
        o[3][nt] = MFMA16(a3, b, o[3][nt]);
      }
    }
    float* dst = outp + (size_t)blk * 16384;
    #pragma unroll
    for (int mt = 0; mt < 4; ++mt)
      #pragma unroll
      for (int r = 0; r < 4; ++r) {
        int row = mt * 16 + row4 + r;
        #pragma unroll
        for (int nt = 0; nt < 2; ++nt)
          dst[row * 256 + w * 32 + nt * 16 + l16] = o[mt][nt][r] + bov[nt];
      }
  }
}

extern "C" void kernel_launch(void* const* d_in, const int* in_sizes, int n_in,
                              void* d_out, int out_size, void* d_ws, size_t ws_size,
                              hipStream_t stream) {
  const float* query   = (const float*)d_in[0];
  const float* context = (const float*)d_in[1];
  const float* fk      = (const float*)d_in[2];
  const float* fv      = (const float*)d_in[3];
  const float* dk      = (const float*)d_in[4];
  const float* dv      = (const float*)d_in[5];
  const float* Wq      = (const float*)d_in[6];
  const float* bq      = (const float*)d_in[7];
  const float* Wg      = (const float*)d_in[8];
  const float* bg      = (const float*)d_in[9];
  const float* Wc1     = (const float*)d_in[10];
  const float* bc1     = (const float*)d_in[11];
  const float* Wc2     = (const float*)d_in[12];
  const float* bc2     = (const float*)d_in[13];
  const float* Wo      = (const float*)d_in[14];
  const float* bo      = (const float*)d_in[15];
  // d_in[16] Ws, d_in[17] bs: dead code (surprise is deleted)
  const float* mixl    = (const float*)d_in[18];
  u16* ws = (u16*)d_ws;
  float* outp = (float*)d_out;

  k_prep<<<368, 256, 0, stream>>>(Wq, Wg, Wc1, Wo, fk, fv, dk, dv, ws);
  k_fused<<<1024, 512, 53760, stream>>>(query, context, bq, bg, bc1, Wc2, bc2, bo,
                                        mixl, ws, outp);
}